// Round 5
// baseline (400.419 us; speedup 1.0000x reference)
//
#include <hip/hip_runtime.h>

#define B_    4
#define C_    256
#define O_    128
#define N_    4096
#define THW   256     // thph row width (theta | phi)
#define TILES 64      // N/64 key tiles

typedef __attribute__((ext_vector_type(8))) _Float16 f16x8;
typedef __attribute__((ext_vector_type(4))) float    f32x4;

struct __align__(8) us4 { unsigned short x, y, z, w; };

__device__ __forceinline__ float bf2f(unsigned short u) {
    unsigned v = ((unsigned)u) << 16;
    union { unsigned u; float f; } c; c.u = v; return c.f;
}
__device__ __forceinline__ unsigned short f2bf(float f) {
    union { float f; unsigned u; } c; c.f = f;
    unsigned r = c.u + 0x7fffu + ((c.u >> 16) & 1u);
    return (unsigned short)(r >> 16);
}
__device__ __forceinline__ unsigned short f2h(float f) {
    _Float16 h = (_Float16)f;
    union { _Float16 h; unsigned short s; } c; c.h = h; return c.s;
}
__device__ __forceinline__ float h2f(unsigned short s) {
    union { unsigned short s; _Float16 h; } c; c.s = s; return (float)c.h;
}

__device__ __forceinline__ void load4f(const void* base, size_t idx, int isf32, float o[4]) {
    if (isf32) {
        float4 v = *(const float4*)((const float*)base + idx);
        o[0] = v.x; o[1] = v.y; o[2] = v.z; o[3] = v.w;
    } else {
        us4 v = *(const us4*)((const unsigned short*)base + idx);
        o[0] = bf2f(v.x); o[1] = bf2f(v.y); o[2] = bf2f(v.z); o[3] = bf2f(v.w);
    }
}
__device__ __forceinline__ float load1f(const void* base, size_t idx, int isf32) {
    return isf32 ? ((const float*)base)[idx] : bf2f(((const unsigned short*)base)[idx]);
}

// ---------------------------------------------------------------------------
// Kernel 0: input dtype detector (fp32 vs bf16) — confirmed fp32 live, kept
// for robustness. Writes flag to ws.
// ---------------------------------------------------------------------------
__global__ __launch_bounds__(256) void detect_kernel(
    const unsigned short* __restrict__ xu, int* __restrict__ flag)
{
    __shared__ int cnt;
    if (threadIdx.x == 0) cnt = 0;
    __syncthreads();
    int local = 0;
    for (int i = threadIdx.x; i < 4096; i += 256) {
        unsigned short u = xu[2 * i];
        int e = (u >> 7) & 0xFF;
        if (e == 0xFF || e >= 0x90 || (e > 0 && e <= 0x60)) local++;
    }
    atomicAdd(&cnt, local);
    __syncthreads();
    if (threadIdx.x == 0) *flag = (cnt > 1024) ? 1 : 0;
}

// ---------------------------------------------------------------------------
// Kernel 1: conv1x1 x3. jsel 0/1 -> thph[b][n][jsel*128+j]; jsel 2 -> gT
// [b][j][n] (transposed via LDS so attention's G staging needs no transpose).
// As transpose-staging uses XOR group swizzle: logical [row][c] stored at
// col ((c>>3) ^ ((row>>2)&7))*8 + (c&7) -> <=2-way bank aliasing (free),
// b128-aligned fragment reads preserved.
// ---------------------------------------------------------------------------
__global__ __launch_bounds__(256) void qkv_kernel(
    const void* __restrict__ x,    // [B][C][N] fp32 or bf16
    const void* __restrict__ wt, const void* __restrict__ wp,
    const void* __restrict__ wg,
    const void* __restrict__ bt, const void* __restrict__ bp,
    const void* __restrict__ bg,
    const int*  __restrict__ flag,
    unsigned short* __restrict__ thph,  // fp16 [B][N][256]
    unsigned short* __restrict__ gT)    // fp16 [B][128][N]
{
    const int isf32 = *flag;
    const int jsel = blockIdx.y;
    const void* w  = jsel == 0 ? wt : (jsel == 1 ? wp : wg);
    const void* bi = jsel == 0 ? bt : (jsel == 1 ? bp : bg);
    const int b  = blockIdx.z;
    const int n0 = blockIdx.x * 64;
    const int tid  = threadIdx.x;
    const int wv   = tid >> 6, lane = tid & 63;
    const int quad = lane >> 4, l16 = lane & 15;

    __shared__ alignas(16) unsigned short smem[64 * 72 + 128 * 72];
    unsigned short (*As)[72] = (unsigned short(*)[72])smem;            // [n][c] swizzled
    unsigned short (*Bs)[72] = (unsigned short(*)[72])(smem + 64 * 72); // [j][c]

    f32x4 acc[8];
    for (int i = 0; i < 8; i++) acc[i] = (f32x4)0.f;

    for (int kc = 0; kc < C_; kc += 64) {
        __syncthreads();
        // stage A: x[b][kc+c][n0+n] -> As[n][c] fp16, swizzled transpose
        for (int it = 0; it < 4; it++) {
            int l = it * 256 + tid;          // [0,1024)
            int c = l >> 4;                  // [0,64)
            int ng = l & 15;                 // n = ng*4 + j
            float v[4];
            load4f(x, (size_t)(b * C_ + kc + c) * N_ + n0 + ng * 4, isf32, v);
            int g = c >> 3, cl = c & 7;
            int swz = ((g ^ (ng & 7)) << 3) + cl;   // row>>2 == ng for j<4
            As[ng * 4 + 0][swz] = f2h(v[0]);
            As[ng * 4 + 1][swz] = f2h(v[1]);
            As[ng * 4 + 2][swz] = f2h(v[2]);
            As[ng * 4 + 3][swz] = f2h(v[3]);
        }
        // stage B: w[j][kc+c] -> Bs[j][c] fp16 (row-contiguous, conflict-free)
        for (int it = 0; it < 8; it++) {
            int l = it * 256 + tid;          // [0,2048)
            int j = l >> 4;                  // [0,128)
            int cg = l & 15;                 // c = cg*4
            float v[4];
            load4f(w, (size_t)j * C_ + kc + cg * 4, isf32, v);
            Bs[j][cg * 4 + 0] = f2h(v[0]);
            Bs[j][cg * 4 + 1] = f2h(v[1]);
            Bs[j][cg * 4 + 2] = f2h(v[2]);
            Bs[j][cg * 4 + 3] = f2h(v[3]);
        }
        __syncthreads();
        for (int s = 0; s < 2; s++) {
            int row = wv * 16 + l16;
            int g2 = ((s * 4 + quad) ^ ((row >> 2) & 7)) << 3;
            f16x8 a = *(const f16x8*)&As[row][g2];
            for (int jt = 0; jt < 8; jt++) {
                f16x8 bb = *(const f16x8*)&Bs[jt * 16 + l16][s * 32 + quad * 8];
                acc[jt] = __builtin_amdgcn_mfma_f32_16x16x32_f16(a, bb, acc[jt], 0, 0, 0);
            }
        }
    }

    // epilogue: D col = lane&15 (j), row = quad*4+reg (n)
    if (jsel < 2) {
        for (int jt = 0; jt < 8; jt++) {
            int j = jt * 16 + l16;
            float bias = load1f(bi, j, isf32);
            for (int r = 0; r < 4; r++) {
                int n = n0 + wv * 16 + quad * 4 + r;
                thph[(size_t)(b * N_ + n) * THW + jsel * O_ + j] = f2h(acc[jt][r] + bias);
            }
        }
    } else {
        // transpose via LDS -> gT[b][j][N] with coalesced global stores
        unsigned short (*T)[68] = (unsigned short(*)[68])smem;  // [j][n_local]
        __syncthreads();
        for (int jt = 0; jt < 8; jt++) {
            int j = jt * 16 + l16;
            float bias = load1f(bi, j, isf32);
            for (int r = 0; r < 4; r++) {
                int nl = wv * 16 + quad * 4 + r;
                T[j][nl] = f2h(acc[jt][r] + bias);
            }
        }
        __syncthreads();
        for (int it = 0; it < 8; it++) {
            int l = it * 256 + tid;   // [0,2048)
            int j = l >> 4;           // [0,128)
            int ng = l & 15;          // n_local = ng*4
            *(us4*)(gT + ((size_t)(b * O_ + j)) * N_ + n0 + ng * 4) = *(const us4*)&T[j][ng * 4];
        }
    }
}

// ---------------------------------------------------------------------------
// Kernel 2: flash-attention partial over a key range (split-K flash-decoding).
// grid (N/64, S, B), block 256 (4 waves x 16 q-rows). Writes unnormalized
// O partial (fp16) + m,l (fp32) per row. G staged straight from gT (no
// transpose -> no bank conflicts).
// ---------------------------------------------------------------------------
__global__ __launch_bounds__(256) void attn_partial(
    const unsigned short* __restrict__ thph,  // fp16 [B][N][256]
    const unsigned short* __restrict__ gT,    // fp16 [B][128][N]
    unsigned short* __restrict__ partO,       // fp16 [S][B][N][128]
    float* __restrict__ pm,                   // [S][B][N]
    float* __restrict__ pl,                   // [S][B][N]
    int S)
{
    const int b    = blockIdx.z;
    const int s_id = blockIdx.y;
    const int n0   = blockIdx.x * 64;
    const int tid  = threadIdx.x;
    const int wv   = tid >> 6, lane = tid & 63;
    const int quad = lane >> 4, l16 = lane & 15;

    const int t0 = (TILES * s_id) / S;
    const int t1 = (TILES * (s_id + 1)) / S;

    __shared__ alignas(16) unsigned short Ks[64][136];   // [key][o]
    __shared__ alignas(16) unsigned short Gs[128][72];   // [o][key] from gT
    __shared__ alignas(16) unsigned short Ps[4][16][72]; // per-wave P tile

    // Q fragments: A[m=q(lane&15)][k=o(s*32+quad*8+i)]
    f16x8 qf[4];
    {
        int qrow = n0 + wv * 16 + l16;
        const unsigned short* qp = thph + (size_t)(b * N_ + qrow) * THW;
        for (int s = 0; s < 4; s++)
            qf[s] = *(const f16x8*)(qp + s * 32 + quad * 8);
    }

    f32x4 oacc[8];
    for (int i = 0; i < 8; i++) oacc[i] = (f32x4)0.f;
    float mstate[4], lstate[4];
    for (int r = 0; r < 4; r++) { mstate[r] = -INFINITY; lstate[r] = 0.f; }

    for (int mt = t0; mt < t1; mt++) {
        int m0 = mt * 64;
        __syncthreads();
        // stage K rows: thph[b][m0+mm][128+o] -> Ks[mm][o] (conflict-free)
        for (int it = 0; it < 8; it++) {
            int l = it * 256 + tid;  // [0,2048)
            int mm = l >> 5;         // [0,64)
            int og = l & 31;         // o = og*4
            us4 v = *(const us4*)(thph + (size_t)(b * N_ + m0 + mm) * THW + O_ + og * 4);
            *(us4*)&Ks[mm][og * 4] = v;
        }
        // stage G^T rows: gT[b][o][m0+mm] -> Gs[o][mm] (row copy, conflict-free)
        for (int it = 0; it < 8; it++) {
            int l = it * 256 + tid;  // [0,2048)
            int o = l >> 4;          // [0,128)
            int ng = l & 15;         // key = ng*4
            us4 v = *(const us4*)(gT + ((size_t)(b * O_ + o)) * N_ + m0 + ng * 4);
            *(us4*)&Gs[o][ng * 4] = v;
        }
        __syncthreads();

        // S = Q K^T : 4 key subtiles x 4 k-steps
        f32x4 sacc[4];
        for (int kt = 0; kt < 4; kt++) sacc[kt] = (f32x4)0.f;
        for (int s = 0; s < 4; s++) {
            for (int kt = 0; kt < 4; kt++) {
                f16x8 kb = *(const f16x8*)&Ks[kt * 16 + l16][s * 32 + quad * 8];
                sacc[kt] = __builtin_amdgcn_mfma_f32_16x16x32_f16(qf[s], kb, sacc[kt], 0, 0, 0);
            }
        }

        // online softmax per owned row (row = quad*4 + r)
        for (int r = 0; r < 4; r++) {
            float rm = fmaxf(fmaxf(sacc[0][r], sacc[1][r]), fmaxf(sacc[2][r], sacc[3][r]));
            for (int off = 1; off < 16; off <<= 1)
                rm = fmaxf(rm, __shfl_xor(rm, off));
            float mnew  = fmaxf(mstate[r], rm);
            float alpha = __expf(mstate[r] - mnew);
            float p0 = __expf(sacc[0][r] - mnew);
            float p1 = __expf(sacc[1][r] - mnew);
            float p2 = __expf(sacc[2][r] - mnew);
            float p3 = __expf(sacc[3][r] - mnew);
            float rs = p0 + p1 + p2 + p3;
            for (int off = 1; off < 16; off <<= 1)
                rs += __shfl_xor(rs, off);
            lstate[r] = lstate[r] * alpha + rs;
            mstate[r] = mnew;
            for (int jt = 0; jt < 8; jt++) oacc[jt][r] *= alpha;
            int row = quad * 4 + r;
            Ps[wv][row][ 0 + l16] = f2h(p0);
            Ps[wv][row][16 + l16] = f2h(p1);
            Ps[wv][row][32 + l16] = f2h(p2);
            Ps[wv][row][48 + l16] = f2h(p3);
        }
        __syncthreads();

        // O += P G
        for (int s = 0; s < 2; s++) {
            f16x8 pa = *(const f16x8*)&Ps[wv][l16][s * 32 + quad * 8];
            for (int jt = 0; jt < 8; jt++) {
                f16x8 gb = *(const f16x8*)&Gs[jt * 16 + l16][s * 32 + quad * 8];
                oacc[jt] = __builtin_amdgcn_mfma_f32_16x16x32_f16(pa, gb, oacc[jt], 0, 0, 0);
            }
        }
    }

    // epilogue: raw partial O + m,l
    for (int r = 0; r < 4; r++) {
        int n = n0 + wv * 16 + quad * 4 + r;
        size_t rowb = ((size_t)(s_id * B_ + b) * N_ + n) * O_;
        for (int jt = 0; jt < 8; jt++)
            partO[rowb + jt * 16 + l16] = f2h(oacc[jt][r]);
        if (l16 == 0) {
            pm[(size_t)(s_id * B_ + b) * N_ + n] = mstate[r];
            pl[(size_t)(s_id * B_ + b) * N_ + n] = lstate[r];
        }
    }
}

// ---------------------------------------------------------------------------
// Kernel 2b: merge split-K partials -> y[b][n][o] (normalized, fp16).
// One thread per 4 o-values. grid = B*N*32/256 = 2048.
// ---------------------------------------------------------------------------
__global__ __launch_bounds__(256) void merge_kernel(
    const unsigned short* __restrict__ partO,  // [S][B][N][128]
    const float* __restrict__ pm, const float* __restrict__ pl,
    unsigned short* __restrict__ y,            // [B][N][128]
    int S)
{
    int idx = blockIdx.x * 256 + threadIdx.x;  // [0, B*N*32)
    int bn  = idx >> 5;                        // b*N + n
    int og  = idx & 31;                        // o = og*4
    const int BN = B_ * N_;

    float M = -INFINITY;
    for (int s = 0; s < S; s++) M = fmaxf(M, pm[(size_t)s * BN + bn]);
    float w[4];
    float L = 0.f;
    for (int s = 0; s < S; s++) {
        w[s] = __expf(pm[(size_t)s * BN + bn] - M);
        L += w[s] * pl[(size_t)s * BN + bn];
    }
    float inv = 1.0f / L;

    float a0 = 0.f, a1 = 0.f, a2 = 0.f, a3 = 0.f;
    for (int s = 0; s < S; s++) {
        us4 v = *(const us4*)(partO + ((size_t)s * BN + bn) * O_ + og * 4);
        a0 += h2f(v.x) * w[s];
        a1 += h2f(v.y) * w[s];
        a2 += h2f(v.z) * w[s];
        a3 += h2f(v.w) * w[s];
    }
    us4 r;
    r.x = f2h(a0 * inv); r.y = f2h(a1 * inv);
    r.z = f2h(a2 * inv); r.w = f2h(a3 * inv);
    *(us4*)(y + (size_t)bn * O_ + og * 4) = r;
}

// ---------------------------------------------------------------------------
// Kernel 3: z[b][c][n] = sum_o wW[c][o] y[b][n][o] + bW[c] + x[b][c][n]
// ---------------------------------------------------------------------------
__global__ __launch_bounds__(256) void out_kernel(
    const unsigned short* __restrict__ y,    // fp16 [B][N][128]
    const void* __restrict__ wW,             // [256][128]
    const void* __restrict__ bW,             // [256]
    const void* __restrict__ x,              // [B][C][N]
    const int*  __restrict__ flag,
    void* __restrict__ z)                    // fp32 or bf16 out
{
    const int isf32 = *flag;
    const int b  = blockIdx.z;
    const int c0 = blockIdx.y * 64;
    const int n0 = blockIdx.x * 128;
    const int tid  = threadIdx.x;
    const int wv   = tid >> 6, lane = tid & 63;
    const int quad = lane >> 4, l16 = lane & 15;

    __shared__ alignas(16) unsigned short Ys[128][136];  // [n][o] fp16
    __shared__ alignas(16) unsigned short Ws[64][136];   // [c][o] fp16

    for (int it = 0; it < 16; it++) {
        int l = it * 256 + tid;   // [0,4096)
        int nn = l >> 5;
        int og = l & 31;
        us4 v = *(const us4*)(y + (size_t)(b * N_ + n0 + nn) * O_ + og * 4);
        *(us4*)&Ys[nn][og * 4] = v;
    }
    for (int it = 0; it < 8; it++) {
        int l = it * 256 + tid;   // [0,2048)
        int cc = l >> 5;
        int og = l & 31;
        float v[4];
        load4f(wW, (size_t)(c0 + cc) * O_ + og * 4, isf32, v);
        Ws[cc][og * 4 + 0] = f2h(v[0]);
        Ws[cc][og * 4 + 1] = f2h(v[1]);
        Ws[cc][og * 4 + 2] = f2h(v[2]);
        Ws[cc][og * 4 + 3] = f2h(v[3]);
    }
    __syncthreads();

    f32x4 acc[8];
    for (int i = 0; i < 8; i++) acc[i] = (f32x4)0.f;
    for (int s = 0; s < 4; s++) {
        f16x8 a = *(const f16x8*)&Ws[wv * 16 + l16][s * 32 + quad * 8];
        for (int nt = 0; nt < 8; nt++) {
            f16x8 bb = *(const f16x8*)&Ys[nt * 16 + l16][s * 32 + quad * 8];
            acc[nt] = __builtin_amdgcn_mfma_f32_16x16x32_f16(a, bb, acc[nt], 0, 0, 0);
        }
    }
    for (int r = 0; r < 4; r++) {
        int c = c0 + wv * 16 + quad * 4 + r;
        float bias = load1f(bW, c, isf32);
        for (int nt = 0; nt < 8; nt++) {
            int n = n0 + nt * 16 + l16;
            size_t idx = (size_t)(b * C_ + c) * N_ + n;
            float zv = acc[nt][r] + bias + load1f(x, idx, isf32);
            if (isf32) ((float*)z)[idx] = zv;
            else       ((unsigned short*)z)[idx] = f2bf(zv);
        }
    }
}

// ---------------------------------------------------------------------------
extern "C" void kernel_launch(void* const* d_in, const int* in_sizes, int n_in,
                              void* d_out, int out_size, void* d_ws, size_t ws_size,
                              hipStream_t stream) {
    const void* x  = d_in[0];
    const void* wt = d_in[1];
    const void* bt = d_in[2];
    const void* wp = d_in[3];
    const void* bp = d_in[4];
    const void* wg = d_in[5];
    const void* bg = d_in[6];
    const void* wW = d_in[7];
    const void* bW = d_in[8];

    // choose split factor from ws_size (constant across calls -> graph-safe)
    const size_t base = 64 /*flag+pad*/ + 8388608 /*thph*/ + 4194304 /*gT*/;
    const size_t per_split = 4194304 /*partO*/ + 131072 /*pm+pl*/;
    int S = 3;
    while (S > 1 && base + (size_t)S * per_split > ws_size) S--;

    char* p = (char*)d_ws;
    int* flag = (int*)p;                    p += 64;
    unsigned short* thph = (unsigned short*)p;  p += 8388608;
    unsigned short* gT   = (unsigned short*)p;  p += 4194304;
    unsigned short* partO = (unsigned short*)p; p += (size_t)S * 4194304;
    float* pm = (float*)p;                  p += (size_t)S * 65536;
    float* pl = (float*)p;
    unsigned short* y = gT;   // gT is dead after attn_partial; merge writes y here

    detect_kernel<<<1, 256, 0, stream>>>((const unsigned short*)x, flag);

    dim3 g1(N_ / 64, 3, B_);
    qkv_kernel<<<g1, 256, 0, stream>>>(x, wt, wp, wg, bt, bp, bg, flag, thph, gT);

    dim3 g2(N_ / 64, S, B_);
    attn_partial<<<g2, 256, 0, stream>>>(thph, gT, partO, pm, pl, S);

    merge_kernel<<<(B_ * N_ * 32) / 256, 256, 0, stream>>>(partO, pm, pl, y, S);

    dim3 g3(N_ / 128, C_ / 64, B_);
    out_kernel<<<g3, 256, 0, stream>>>(y, wW, bW, x, flag, d_out);
}

// Round 6
// 273.510 us; speedup vs baseline: 1.4640x; 1.4640x over previous
//
#include <hip/hip_runtime.h>

#define B_    4
#define C_    256
#define O_    128
#define N_    4096
#define THW   256     // thph row width (theta | phi)
#define TILES 64      // N/64 key tiles (attn uses TK=64)

typedef __attribute__((ext_vector_type(8))) _Float16 f16x8;
typedef __attribute__((ext_vector_type(4))) float    f32x4;

struct __align__(8) us4 { unsigned short x, y, z, w; };

__device__ __forceinline__ float bf2f(unsigned short u) {
    unsigned v = ((unsigned)u) << 16;
    union { unsigned u; float f; } c; c.u = v; return c.f;
}
__device__ __forceinline__ unsigned short f2bf(float f) {
    union { float f; unsigned u; } c; c.f = f;
    unsigned r = c.u + 0x7fffu + ((c.u >> 16) & 1u);
    return (unsigned short)(r >> 16);
}
__device__ __forceinline__ unsigned short f2h(float f) {
    _Float16 h = (_Float16)f;
    union { _Float16 h; unsigned short s; } c; c.h = h; return c.s;
}
__device__ __forceinline__ float h2f(unsigned short s) {
    union { unsigned short s; _Float16 h; } c; c.s = s; return (float)c.h;
}

__device__ __forceinline__ void load4f(const void* base, size_t idx, int isf32, float o[4]) {
    if (isf32) {
        float4 v = *(const float4*)((const float*)base + idx);
        o[0] = v.x; o[1] = v.y; o[2] = v.z; o[3] = v.w;
    } else {
        us4 v = *(const us4*)((const unsigned short*)base + idx);
        o[0] = bf2f(v.x); o[1] = bf2f(v.y); o[2] = bf2f(v.z); o[3] = bf2f(v.w);
    }
}
__device__ __forceinline__ float load1f(const void* base, size_t idx, int isf32) {
    return isf32 ? ((const float*)base)[idx] : bf2f(((const unsigned short*)base)[idx]);
}

// ---------------------------------------------------------------------------
// Kernel 0: input dtype detector (fp32 confirmed live; kept for robustness).
// ---------------------------------------------------------------------------
__global__ __launch_bounds__(256) void detect_kernel(
    const unsigned short* __restrict__ xu, int* __restrict__ flag)
{
    __shared__ int cnt;
    if (threadIdx.x == 0) cnt = 0;
    __syncthreads();
    int local = 0;
    for (int i = threadIdx.x; i < 4096; i += 256) {
        unsigned short u = xu[2 * i];
        int e = (u >> 7) & 0xFF;
        if (e == 0xFF || e >= 0x90 || (e > 0 && e <= 0x60)) local++;
    }
    atomicAdd(&cnt, local);
    __syncthreads();
    if (threadIdx.x == 0) *flag = (cnt > 1024) ? 1 : 0;
}

// ---------------------------------------------------------------------------
// Kernel 1: conv1x1 x3 -> thph [B][N][256] (theta|phi), gT [B][128][N].
// (unchanged from round 5 — swizzled As transpose, conflict-free)
// ---------------------------------------------------------------------------
__global__ __launch_bounds__(256) void qkv_kernel(
    const void* __restrict__ x,
    const void* __restrict__ wt, const void* __restrict__ wp,
    const void* __restrict__ wg,
    const void* __restrict__ bt, const void* __restrict__ bp,
    const void* __restrict__ bg,
    const int*  __restrict__ flag,
    unsigned short* __restrict__ thph,
    unsigned short* __restrict__ gT)
{
    const int isf32 = *flag;
    const int jsel = blockIdx.y;
    const void* w  = jsel == 0 ? wt : (jsel == 1 ? wp : wg);
    const void* bi = jsel == 0 ? bt : (jsel == 1 ? bp : bg);
    const int b  = blockIdx.z;
    const int n0 = blockIdx.x * 64;
    const int tid  = threadIdx.x;
    const int wv   = tid >> 6, lane = tid & 63;
    const int quad = lane >> 4, l16 = lane & 15;

    __shared__ alignas(16) unsigned short smem[64 * 72 + 128 * 72];
    unsigned short (*As)[72] = (unsigned short(*)[72])smem;
    unsigned short (*Bs)[72] = (unsigned short(*)[72])(smem + 64 * 72);

    f32x4 acc[8];
    for (int i = 0; i < 8; i++) acc[i] = (f32x4)0.f;

    for (int kc = 0; kc < C_; kc += 64) {
        __syncthreads();
        for (int it = 0; it < 4; it++) {
            int l = it * 256 + tid;
            int c = l >> 4;
            int ng = l & 15;
            float v[4];
            load4f(x, (size_t)(b * C_ + kc + c) * N_ + n0 + ng * 4, isf32, v);
            int g = c >> 3, cl = c & 7;
            int swz = ((g ^ (ng & 7)) << 3) + cl;
            As[ng * 4 + 0][swz] = f2h(v[0]);
            As[ng * 4 + 1][swz] = f2h(v[1]);
            As[ng * 4 + 2][swz] = f2h(v[2]);
            As[ng * 4 + 3][swz] = f2h(v[3]);
        }
        for (int it = 0; it < 8; it++) {
            int l = it * 256 + tid;
            int j = l >> 4;
            int cg = l & 15;
            float v[4];
            load4f(w, (size_t)j * C_ + kc + cg * 4, isf32, v);
            Bs[j][cg * 4 + 0] = f2h(v[0]);
            Bs[j][cg * 4 + 1] = f2h(v[1]);
            Bs[j][cg * 4 + 2] = f2h(v[2]);
            Bs[j][cg * 4 + 3] = f2h(v[3]);
        }
        __syncthreads();
        for (int s = 0; s < 2; s++) {
            int row = wv * 16 + l16;
            int g2 = ((s * 4 + quad) ^ ((row >> 2) & 7)) << 3;
            f16x8 a = *(const f16x8*)&As[row][g2];
            for (int jt = 0; jt < 8; jt++) {
                f16x8 bb = *(const f16x8*)&Bs[jt * 16 + l16][s * 32 + quad * 8];
                acc[jt] = __builtin_amdgcn_mfma_f32_16x16x32_f16(a, bb, acc[jt], 0, 0, 0);
            }
        }
    }

    if (jsel < 2) {
        for (int jt = 0; jt < 8; jt++) {
            int j = jt * 16 + l16;
            float bias = load1f(bi, j, isf32);
            for (int r = 0; r < 4; r++) {
                int n = n0 + wv * 16 + quad * 4 + r;
                thph[(size_t)(b * N_ + n) * THW + jsel * O_ + j] = f2h(acc[jt][r] + bias);
            }
        }
    } else {
        unsigned short (*T)[68] = (unsigned short(*)[68])smem;
        __syncthreads();
        for (int jt = 0; jt < 8; jt++) {
            int j = jt * 16 + l16;
            float bias = load1f(bi, j, isf32);
            for (int r = 0; r < 4; r++) {
                int nl = wv * 16 + quad * 4 + r;
                T[j][nl] = f2h(acc[jt][r] + bias);
            }
        }
        __syncthreads();
        for (int it = 0; it < 8; it++) {
            int l = it * 256 + tid;
            int j = l >> 4;
            int ng = l & 15;
            *(us4*)(gT + ((size_t)(b * O_ + j)) * N_ + n0 + ng * 4) = *(const us4*)&T[j][ng * 4];
        }
    }
}

// ---------------------------------------------------------------------------
// Kernel 2: flash-attention partial. 512 threads = 8 waves (2/SIMD for
// intra-SIMD latency overlap). Q-tile 128 rows (16/wave), TK=64 keys.
// grid (N/128, S, B) with S=2 -> 256 blocks = exactly 1/CU. LDS 54 KB.
// Softmax restructured into interleaved 4-row phases (ILP on shfl trees).
// ---------------------------------------------------------------------------
__global__ __launch_bounds__(512) void attn_partial(
    const unsigned short* __restrict__ thph,  // fp16 [B][N][256]
    const unsigned short* __restrict__ gT,    // fp16 [B][128][N]
    unsigned short* __restrict__ partO,       // fp16 [S][B][N][128]
    float* __restrict__ pm,                   // [S][B][N]
    float* __restrict__ pl,                   // [S][B][N]
    int S)
{
    const int b    = blockIdx.z;
    const int s_id = blockIdx.y;
    const int n0   = blockIdx.x * 128;
    const int tid  = threadIdx.x;
    const int wv   = tid >> 6, lane = tid & 63;
    const int quad = lane >> 4, l16 = lane & 15;

    const int t0 = (TILES * s_id) / S;
    const int t1 = (TILES * (s_id + 1)) / S;

    __shared__ alignas(16) unsigned short Ks[64][136];   // 17.4 KB [key][o]
    __shared__ alignas(16) unsigned short Gs[128][72];   // 18.4 KB [o][key]
    __shared__ alignas(16) unsigned short Ps[8][16][72]; // 18.4 KB per-wave P

    // Q fragments: A[m=q(l16)][k=o]
    f16x8 qf[4];
    {
        int qrow = n0 + wv * 16 + l16;
        const unsigned short* qp = thph + (size_t)(b * N_ + qrow) * THW;
        for (int s = 0; s < 4; s++)
            qf[s] = *(const f16x8*)(qp + s * 32 + quad * 8);
    }

    f32x4 oacc[8];
    for (int i = 0; i < 8; i++) oacc[i] = (f32x4)0.f;
    float mstate[4], lstate[4];
    for (int r = 0; r < 4; r++) { mstate[r] = -INFINITY; lstate[r] = 0.f; }

    for (int mt = t0; mt < t1; mt++) {
        int m0 = mt * 64;
        __syncthreads();
        // stage K: thph[b][m0+mm][128+o] -> Ks[mm][o]; 512 thr x 4 it
        for (int it = 0; it < 4; it++) {
            int l = it * 512 + tid;  // [0,2048)
            int mm = l >> 5;         // [0,64)
            int og = l & 31;
            us4 v = *(const us4*)(thph + (size_t)(b * N_ + m0 + mm) * THW + O_ + og * 4);
            *(us4*)&Ks[mm][og * 4] = v;
        }
        // stage G^T rows: gT[b][o][m0+..] -> Gs[o][..]; 512 thr x 4 it
        for (int it = 0; it < 4; it++) {
            int l = it * 512 + tid;  // [0,2048)
            int o = l >> 4;          // [0,128)
            int ng = l & 15;         // key = ng*4
            us4 v = *(const us4*)(gT + ((size_t)(b * O_ + o)) * N_ + m0 + ng * 4);
            *(us4*)&Gs[o][ng * 4] = v;
        }
        __syncthreads();

        // S = Q K^T
        f32x4 sacc[4];
        for (int kt = 0; kt < 4; kt++) sacc[kt] = (f32x4)0.f;
        for (int s = 0; s < 4; s++) {
            for (int kt = 0; kt < 4; kt++) {
                f16x8 kb = *(const f16x8*)&Ks[kt * 16 + l16][s * 32 + quad * 8];
                sacc[kt] = __builtin_amdgcn_mfma_f32_16x16x32_f16(qf[s], kb, sacc[kt], 0, 0, 0);
            }
        }

        // ---- online softmax, phase-interleaved across the 4 owned rows ----
        float rm[4], al[4], rs[4];
        #pragma unroll
        for (int r = 0; r < 4; r++)
            rm[r] = fmaxf(fmaxf(sacc[0][r], sacc[1][r]), fmaxf(sacc[2][r], sacc[3][r]));
        #pragma unroll
        for (int off = 1; off < 16; off <<= 1) {
            #pragma unroll
            for (int r = 0; r < 4; r++)
                rm[r] = fmaxf(rm[r], __shfl_xor(rm[r], off));
        }
        #pragma unroll
        for (int r = 0; r < 4; r++) {
            float mnew = fmaxf(mstate[r], rm[r]);
            al[r] = __expf(mstate[r] - mnew);
            mstate[r] = mnew;
        }
        #pragma unroll
        for (int r = 0; r < 4; r++) {
            int row = quad * 4 + r;
            float p0 = __expf(sacc[0][r] - mstate[r]);
            float p1 = __expf(sacc[1][r] - mstate[r]);
            float p2 = __expf(sacc[2][r] - mstate[r]);
            float p3 = __expf(sacc[3][r] - mstate[r]);
            rs[r] = (p0 + p1) + (p2 + p3);
            Ps[wv][row][ 0 + l16] = f2h(p0);
            Ps[wv][row][16 + l16] = f2h(p1);
            Ps[wv][row][32 + l16] = f2h(p2);
            Ps[wv][row][48 + l16] = f2h(p3);
        }
        #pragma unroll
        for (int off = 1; off < 16; off <<= 1) {
            #pragma unroll
            for (int r = 0; r < 4; r++)
                rs[r] += __shfl_xor(rs[r], off);
        }
        #pragma unroll
        for (int r = 0; r < 4; r++) {
            lstate[r] = lstate[r] * al[r] + rs[r];
            #pragma unroll
            for (int jt = 0; jt < 8; jt++) oacc[jt][r] *= al[r];
        }
        __syncthreads();

        // O += P G
        for (int s = 0; s < 2; s++) {
            f16x8 pa = *(const f16x8*)&Ps[wv][l16][s * 32 + quad * 8];
            for (int jt = 0; jt < 8; jt++) {
                f16x8 gb = *(const f16x8*)&Gs[jt * 16 + l16][s * 32 + quad * 8];
                oacc[jt] = __builtin_amdgcn_mfma_f32_16x16x32_f16(pa, gb, oacc[jt], 0, 0, 0);
            }
        }
    }

    // epilogue: raw partial O + m,l
    for (int r = 0; r < 4; r++) {
        int n = n0 + wv * 16 + quad * 4 + r;
        size_t rowb = ((size_t)(s_id * B_ + b) * N_ + n) * O_;
        for (int jt = 0; jt < 8; jt++)
            partO[rowb + jt * 16 + l16] = f2h(oacc[jt][r]);
        if (l16 == 0) {
            pm[(size_t)(s_id * B_ + b) * N_ + n] = mstate[r];
            pl[(size_t)(s_id * B_ + b) * N_ + n] = lstate[r];
        }
    }
}

// ---------------------------------------------------------------------------
// Kernel 2b: merge split-K partials -> y[b][n][o] (normalized fp16).
// ---------------------------------------------------------------------------
__global__ __launch_bounds__(256) void merge_kernel(
    const unsigned short* __restrict__ partO,
    const float* __restrict__ pm, const float* __restrict__ pl,
    unsigned short* __restrict__ y,
    int S)
{
    int idx = blockIdx.x * 256 + threadIdx.x;
    int bn  = idx >> 5;
    int og  = idx & 31;
    const int BN = B_ * N_;

    float M = -INFINITY;
    for (int s = 0; s < S; s++) M = fmaxf(M, pm[(size_t)s * BN + bn]);
    float w[4];
    float L = 0.f;
    for (int s = 0; s < S; s++) {
        w[s] = __expf(pm[(size_t)s * BN + bn] - M);
        L += w[s] * pl[(size_t)s * BN + bn];
    }
    float inv = 1.0f / L;

    float a0 = 0.f, a1 = 0.f, a2 = 0.f, a3 = 0.f;
    for (int s = 0; s < S; s++) {
        us4 v = *(const us4*)(partO + ((size_t)s * BN + bn) * O_ + og * 4);
        a0 += h2f(v.x) * w[s];
        a1 += h2f(v.y) * w[s];
        a2 += h2f(v.z) * w[s];
        a3 += h2f(v.w) * w[s];
    }
    us4 r;
    r.x = f2h(a0 * inv); r.y = f2h(a1 * inv);
    r.z = f2h(a2 * inv); r.w = f2h(a3 * inv);
    *(us4*)(y + (size_t)bn * O_ + og * 4) = r;
}

// ---------------------------------------------------------------------------
// Kernel 3: z[b][c][n] = sum_o wW[c][o] y[b][n][o] + bW[c] + x[b][c][n]
// ---------------------------------------------------------------------------
__global__ __launch_bounds__(256) void out_kernel(
    const unsigned short* __restrict__ y,
    const void* __restrict__ wW,
    const void* __restrict__ bW,
    const void* __restrict__ x,
    const int*  __restrict__ flag,
    void* __restrict__ z)
{
    const int isf32 = *flag;
    const int b  = blockIdx.z;
    const int c0 = blockIdx.y * 64;
    const int n0 = blockIdx.x * 128;
    const int tid  = threadIdx.x;
    const int wv   = tid >> 6, lane = tid & 63;
    const int quad = lane >> 4, l16 = lane & 15;

    __shared__ alignas(16) unsigned short Ys[128][136];
    __shared__ alignas(16) unsigned short Ws[64][136];

    for (int it = 0; it < 16; it++) {
        int l = it * 256 + tid;
        int nn = l >> 5;
        int og = l & 31;
        us4 v = *(const us4*)(y + (size_t)(b * N_ + n0 + nn) * O_ + og * 4);
        *(us4*)&Ys[nn][og * 4] = v;
    }
    for (int it = 0; it < 8; it++) {
        int l = it * 256 + tid;
        int cc = l >> 5;
        int og = l & 31;
        float v[4];
        load4f(wW, (size_t)(c0 + cc) * O_ + og * 4, isf32, v);
        Ws[cc][og * 4 + 0] = f2h(v[0]);
        Ws[cc][og * 4 + 1] = f2h(v[1]);
        Ws[cc][og * 4 + 2] = f2h(v[2]);
        Ws[cc][og * 4 + 3] = f2h(v[3]);
    }
    __syncthreads();

    f32x4 acc[8];
    for (int i = 0; i < 8; i++) acc[i] = (f32x4)0.f;
    for (int s = 0; s < 4; s++) {
        f16x8 a = *(const f16x8*)&Ws[wv * 16 + l16][s * 32 + quad * 8];
        for (int nt = 0; nt < 8; nt++) {
            f16x8 bb = *(const f16x8*)&Ys[nt * 16 + l16][s * 32 + quad * 8];
            acc[nt] = __builtin_amdgcn_mfma_f32_16x16x32_f16(a, bb, acc[nt], 0, 0, 0);
        }
    }
    for (int r = 0; r < 4; r++) {
        int c = c0 + wv * 16 + quad * 4 + r;
        float bias = load1f(bW, c, isf32);
        for (int nt = 0; nt < 8; nt++) {
            int n = n0 + nt * 16 + l16;
            size_t idx = (size_t)(b * C_ + c) * N_ + n;
            float zv = acc[nt][r] + bias + load1f(x, idx, isf32);
            if (isf32) ((float*)z)[idx] = zv;
            else       ((unsigned short*)z)[idx] = f2bf(zv);
        }
    }
}

// ---------------------------------------------------------------------------
extern "C" void kernel_launch(void* const* d_in, const int* in_sizes, int n_in,
                              void* d_out, int out_size, void* d_ws, size_t ws_size,
                              hipStream_t stream) {
    const void* x  = d_in[0];
    const void* wt = d_in[1];
    const void* bt = d_in[2];
    const void* wp = d_in[3];
    const void* bp = d_in[4];
    const void* wg = d_in[5];
    const void* bg = d_in[6];
    const void* wW = d_in[7];
    const void* bW = d_in[8];

    // split factor from ws_size (constant across calls -> graph-safe)
    const size_t base = 64 + 8388608 /*thph*/ + 4194304 /*gT*/;
    const size_t per_split = 4194304 /*partO*/ + 131072 /*pm+pl*/;
    int S = 2;
    while (S > 1 && base + (size_t)S * per_split > ws_size) S--;

    char* p = (char*)d_ws;
    int* flag = (int*)p;                    p += 64;
    unsigned short* thph = (unsigned short*)p;  p += 8388608;
    unsigned short* gT   = (unsigned short*)p;  p += 4194304;
    unsigned short* partO = (unsigned short*)p; p += (size_t)S * 4194304;
    float* pm = (float*)p;                  p += (size_t)S * 65536;
    float* pl = (float*)p;
    unsigned short* y = gT;   // gT dead after attn_partial; reuse for y

    detect_kernel<<<1, 256, 0, stream>>>((const unsigned short*)x, flag);

    dim3 g1(N_ / 64, 3, B_);
    qkv_kernel<<<g1, 256, 0, stream>>>(x, wt, wp, wg, bt, bp, bg, flag, thph, gT);

    dim3 g2(N_ / 128, S, B_);
    attn_partial<<<g2, 512, 0, stream>>>(thph, gT, partO, pm, pl, S);

    merge_kernel<<<(B_ * N_ * 32) / 256, 256, 0, stream>>>(partO, pm, pl, y, S);

    dim3 g3(N_ / 128, C_ / 64, B_);
    out_kernel<<<g3, 256, 0, stream>>>(y, wW, bW, x, flag, d_out);
}

// Round 7
// 187.211 us; speedup vs baseline: 2.1389x; 1.4610x over previous
//
#include <hip/hip_runtime.h>

#define B_    4
#define C_    256
#define O_    128
#define N_    4096
#define THW   256     // thph row width (theta | phi)
#define TILES 64      // N/64 key tiles (attn uses TK=64)

typedef __attribute__((ext_vector_type(8))) _Float16 f16x8;
typedef __attribute__((ext_vector_type(4))) float    f32x4;

struct __align__(8) us4 { unsigned short x, y, z, w; };

__device__ __forceinline__ float bf2f(unsigned short u) {
    unsigned v = ((unsigned)u) << 16;
    union { unsigned u; float f; } c; c.u = v; return c.f;
}
__device__ __forceinline__ unsigned short f2bf(float f) {
    union { float f; unsigned u; } c; c.f = f;
    unsigned r = c.u + 0x7fffu + ((c.u >> 16) & 1u);
    return (unsigned short)(r >> 16);
}
__device__ __forceinline__ unsigned short f2h(float f) {
    _Float16 h = (_Float16)f;
    union { _Float16 h; unsigned short s; } c; c.h = h; return c.s;
}
__device__ __forceinline__ float h2f(unsigned short s) {
    union { unsigned short s; _Float16 h; } c; c.s = s; return (float)c.h;
}

__device__ __forceinline__ void load4f(const void* base, size_t idx, int isf32, float o[4]) {
    if (isf32) {
        float4 v = *(const float4*)((const float*)base + idx);
        o[0] = v.x; o[1] = v.y; o[2] = v.z; o[3] = v.w;
    } else {
        us4 v = *(const us4*)((const unsigned short*)base + idx);
        o[0] = bf2f(v.x); o[1] = bf2f(v.y); o[2] = bf2f(v.z); o[3] = bf2f(v.w);
    }
}
__device__ __forceinline__ float load1f(const void* base, size_t idx, int isf32) {
    return isf32 ? ((const float*)base)[idx] : bf2f(((const unsigned short*)base)[idx]);
}

// ---------------------------------------------------------------------------
// Kernel 0: input dtype detector (fp32 confirmed live; kept for robustness).
// ---------------------------------------------------------------------------
__global__ __launch_bounds__(256) void detect_kernel(
    const unsigned short* __restrict__ xu, int* __restrict__ flag)
{
    __shared__ int cnt;
    if (threadIdx.x == 0) cnt = 0;
    __syncthreads();
    int local = 0;
    for (int i = threadIdx.x; i < 4096; i += 256) {
        unsigned short u = xu[2 * i];
        int e = (u >> 7) & 0xFF;
        if (e == 0xFF || e >= 0x90 || (e > 0 && e <= 0x60)) local++;
    }
    atomicAdd(&cnt, local);
    __syncthreads();
    if (threadIdx.x == 0) *flag = (cnt > 1024) ? 1 : 0;
}

// ---------------------------------------------------------------------------
// Kernel 1: conv1x1 x3 -> thph [B][N][256] (theta|phi), gT [B][128][N].
// (unchanged — swizzled As transpose, conflict-free)
// ---------------------------------------------------------------------------
__global__ __launch_bounds__(256) void qkv_kernel(
    const void* __restrict__ x,
    const void* __restrict__ wt, const void* __restrict__ wp,
    const void* __restrict__ wg,
    const void* __restrict__ bt, const void* __restrict__ bp,
    const void* __restrict__ bg,
    const int*  __restrict__ flag,
    unsigned short* __restrict__ thph,
    unsigned short* __restrict__ gT)
{
    const int isf32 = *flag;
    const int jsel = blockIdx.y;
    const void* w  = jsel == 0 ? wt : (jsel == 1 ? wp : wg);
    const void* bi = jsel == 0 ? bt : (jsel == 1 ? bp : bg);
    const int b  = blockIdx.z;
    const int n0 = blockIdx.x * 64;
    const int tid  = threadIdx.x;
    const int wv   = tid >> 6, lane = tid & 63;
    const int quad = lane >> 4, l16 = lane & 15;

    __shared__ alignas(16) unsigned short smem[64 * 72 + 128 * 72];
    unsigned short (*As)[72] = (unsigned short(*)[72])smem;
    unsigned short (*Bs)[72] = (unsigned short(*)[72])(smem + 64 * 72);

    f32x4 acc[8];
    for (int i = 0; i < 8; i++) acc[i] = (f32x4)0.f;

    for (int kc = 0; kc < C_; kc += 64) {
        __syncthreads();
        for (int it = 0; it < 4; it++) {
            int l = it * 256 + tid;
            int c = l >> 4;
            int ng = l & 15;
            float v[4];
            load4f(x, (size_t)(b * C_ + kc + c) * N_ + n0 + ng * 4, isf32, v);
            int g = c >> 3, cl = c & 7;
            int swz = ((g ^ (ng & 7)) << 3) + cl;
            As[ng * 4 + 0][swz] = f2h(v[0]);
            As[ng * 4 + 1][swz] = f2h(v[1]);
            As[ng * 4 + 2][swz] = f2h(v[2]);
            As[ng * 4 + 3][swz] = f2h(v[3]);
        }
        for (int it = 0; it < 8; it++) {
            int l = it * 256 + tid;
            int j = l >> 4;
            int cg = l & 15;
            float v[4];
            load4f(w, (size_t)j * C_ + kc + cg * 4, isf32, v);
            Bs[j][cg * 4 + 0] = f2h(v[0]);
            Bs[j][cg * 4 + 1] = f2h(v[1]);
            Bs[j][cg * 4 + 2] = f2h(v[2]);
            Bs[j][cg * 4 + 3] = f2h(v[3]);
        }
        __syncthreads();
        for (int s = 0; s < 2; s++) {
            int row = wv * 16 + l16;
            int g2 = ((s * 4 + quad) ^ ((row >> 2) & 7)) << 3;
            f16x8 a = *(const f16x8*)&As[row][g2];
            for (int jt = 0; jt < 8; jt++) {
                f16x8 bb = *(const f16x8*)&Bs[jt * 16 + l16][s * 32 + quad * 8];
                acc[jt] = __builtin_amdgcn_mfma_f32_16x16x32_f16(a, bb, acc[jt], 0, 0, 0);
            }
        }
    }

    if (jsel < 2) {
        for (int jt = 0; jt < 8; jt++) {
            int j = jt * 16 + l16;
            float bias = load1f(bi, j, isf32);
            for (int r = 0; r < 4; r++) {
                int n = n0 + wv * 16 + quad * 4 + r;
                thph[(size_t)(b * N_ + n) * THW + jsel * O_ + j] = f2h(acc[jt][r] + bias);
            }
        }
    } else {
        unsigned short (*T)[68] = (unsigned short(*)[68])smem;
        __syncthreads();
        for (int jt = 0; jt < 8; jt++) {
            int j = jt * 16 + l16;
            float bias = load1f(bi, j, isf32);
            for (int r = 0; r < 4; r++) {
                int nl = wv * 16 + quad * 4 + r;
                T[j][nl] = f2h(acc[jt][r] + bias);
            }
        }
        __syncthreads();
        for (int it = 0; it < 8; it++) {
            int l = it * 256 + tid;
            int j = l >> 4;
            int ng = l & 15;
            *(us4*)(gT + ((size_t)(b * O_ + j)) * N_ + n0 + ng * 4) = *(const us4*)&T[j][ng * 4];
        }
    }
}

// ---------------------------------------------------------------------------
// Kernel 2: flash-attention partial. 512 threads = 8 waves, Q-tile 128.
// grid (N/128, S, B); S=4 -> 512 blocks = 2 blocks/CU co-resident (LDS
// 2x54KB <= 160, VGPR capped 128 via launch_bounds(512,4)).
// - register prefetch of next tile's K/G (loads in flight across barrier)
// - S computed transposed (K Q^T): per-lane holds 16 keys of ONE query ->
//   softmax reduce = in-lane 16 + 2 shfl hops (xor 16,32); P write = 4x8B
// - 2 barriers/tile (Ps is per-wave, needs no barrier)
// ---------------------------------------------------------------------------
__global__ __launch_bounds__(512, 4) void attn_partial(
    const unsigned short* __restrict__ thph,  // fp16 [B][N][256]
    const unsigned short* __restrict__ gT,    // fp16 [B][128][N]
    unsigned short* __restrict__ partO,       // fp16 [S][B][N][128]
    float* __restrict__ pm,                   // [S][B][N]
    float* __restrict__ pl,                   // [S][B][N]
    int S)
{
    const int b    = blockIdx.z;
    const int s_id = blockIdx.y;
    const int n0   = blockIdx.x * 128;
    const int tid  = threadIdx.x;
    const int wv   = tid >> 6, lane = tid & 63;
    const int quad = lane >> 4, l16 = lane & 15;

    const int t0 = (TILES * s_id) / S;
    const int t1 = (TILES * (s_id + 1)) / S;

    __shared__ alignas(16) unsigned short Ks[64][136];   // [key][o]
    __shared__ alignas(16) unsigned short Gs[128][72];   // [o][key]
    __shared__ alignas(16) unsigned short Ps[8][16][72]; // per-wave P [q][key]

    // Q fragments (used as the B operand of K Q^T): [n=q(l16)][k=o]
    f16x8 qf[4];
    {
        int qrow = n0 + wv * 16 + l16;
        const unsigned short* qp = thph + (size_t)(b * N_ + qrow) * THW;
        for (int s = 0; s < 4; s++)
            qf[s] = *(const f16x8*)(qp + s * 32 + quad * 8);
    }

    f32x4 oacc[8];
    for (int i = 0; i < 8; i++) oacc[i] = (f32x4)0.f;
    // per-lane online-softmax state for query l16 (replicated across quads)
    float mstate = -INFINITY, lstate = 0.f;

    us4 kreg[4], greg[4];
    auto prefetch = [&](int mt) {
        int m0 = mt * 64;
        #pragma unroll
        for (int it = 0; it < 4; it++) {
            int l = it * 512 + tid;          // [0,2048)
            int mm = l >> 5, og = l & 31;
            kreg[it] = *(const us4*)(thph + (size_t)(b * N_ + m0 + mm) * THW + O_ + og * 4);
        }
        #pragma unroll
        for (int it = 0; it < 4; it++) {
            int l = it * 512 + tid;          // [0,2048)
            int o = l >> 4, ng = l & 15;
            greg[it] = *(const us4*)(gT + ((size_t)(b * O_ + o)) * N_ + m0 + ng * 4);
        }
    };
    prefetch(t0);

    for (int mt = t0; mt < t1; mt++) {
        __syncthreads();   // prior tile's LDS reads complete
        // regs -> LDS (vmcnt drain lands here, after the barrier)
        #pragma unroll
        for (int it = 0; it < 4; it++) {
            int l = it * 512 + tid;
            int mm = l >> 5, og = l & 31;
            *(us4*)&Ks[mm][og * 4] = kreg[it];
        }
        #pragma unroll
        for (int it = 0; it < 4; it++) {
            int l = it * 512 + tid;
            int o = l >> 4, ng = l & 15;
            *(us4*)&Gs[o][ng * 4] = greg[it];
        }
        __syncthreads();   // staging visible
        if (mt + 1 < t1) prefetch(mt + 1);   // in flight across compute

        // S^T = K Q^T : D[row=key-sub(quad*4+r)][col=q(l16)]
        f32x4 sacc[4];
        for (int kt = 0; kt < 4; kt++) sacc[kt] = (f32x4)0.f;
        for (int s = 0; s < 4; s++) {
            for (int kt = 0; kt < 4; kt++) {
                f16x8 kb = *(const f16x8*)&Ks[kt * 16 + l16][s * 32 + quad * 8];
                sacc[kt] = __builtin_amdgcn_mfma_f32_16x16x32_f16(kb, qf[s], sacc[kt], 0, 0, 0);
            }
        }

        // online softmax for query l16: in-lane 16 keys + 2 shfl hops
        float rm = fmaxf(fmaxf(fmaxf(sacc[0][0], sacc[0][1]), fmaxf(sacc[0][2], sacc[0][3])),
                         fmaxf(fmaxf(sacc[1][0], sacc[1][1]), fmaxf(sacc[1][2], sacc[1][3])));
        rm = fmaxf(rm, fmaxf(fmaxf(fmaxf(sacc[2][0], sacc[2][1]), fmaxf(sacc[2][2], sacc[2][3])),
                             fmaxf(fmaxf(sacc[3][0], sacc[3][1]), fmaxf(sacc[3][2], sacc[3][3]))));
        rm = fmaxf(rm, __shfl_xor(rm, 16));
        rm = fmaxf(rm, __shfl_xor(rm, 32));

        float mnew  = fmaxf(mstate, rm);
        float alpha = __expf(mstate - mnew);
        mstate = mnew;

        float rs = 0.f;
        #pragma unroll
        for (int kt = 0; kt < 4; kt++) {
            float p0 = __expf(sacc[kt][0] - mnew);
            float p1 = __expf(sacc[kt][1] - mnew);
            float p2 = __expf(sacc[kt][2] - mnew);
            float p3 = __expf(sacc[kt][3] - mnew);
            rs += (p0 + p1) + (p2 + p3);
            us4 pk;
            pk.x = f2h(p0); pk.y = f2h(p1); pk.z = f2h(p2); pk.w = f2h(p3);
            *(us4*)&Ps[wv][l16][kt * 16 + quad * 4] = pk;   // [q][key] packed 8B
        }
        rs += __shfl_xor(rs, 16);
        rs += __shfl_xor(rs, 32);
        lstate = lstate * alpha + rs;

        // broadcast alpha to the O-rows this lane accumulates (q = quad*4+r)
        float av[4];
        #pragma unroll
        for (int r = 0; r < 4; r++) av[r] = __shfl(alpha, quad * 4 + r);
        #pragma unroll
        for (int jt = 0; jt < 8; jt++)
            #pragma unroll
            for (int r = 0; r < 4; r++) oacc[jt][r] *= av[r];

        // O += P G  (Ps is per-wave: no barrier needed; lgkmcnt handles order)
        for (int s = 0; s < 2; s++) {
            f16x8 pa = *(const f16x8*)&Ps[wv][l16][s * 32 + quad * 8];
            for (int jt = 0; jt < 8; jt++) {
                f16x8 gb = *(const f16x8*)&Gs[jt * 16 + l16][s * 32 + quad * 8];
                oacc[jt] = __builtin_amdgcn_mfma_f32_16x16x32_f16(pa, gb, oacc[jt], 0, 0, 0);
            }
        }
    }

    // epilogue: raw partial O (rows q=quad*4+r) + m,l (held at lanes by l16)
    for (int r = 0; r < 4; r++) {
        int n = n0 + wv * 16 + quad * 4 + r;
        size_t rowb = ((size_t)(s_id * B_ + b) * N_ + n) * O_;
        for (int jt = 0; jt < 8; jt++)
            partO[rowb + jt * 16 + l16] = f2h(oacc[jt][r]);
    }
    if (quad == 0) {
        int n = n0 + wv * 16 + l16;
        pm[(size_t)(s_id * B_ + b) * N_ + n] = mstate;
        pl[(size_t)(s_id * B_ + b) * N_ + n] = lstate;
    }
}

// ---------------------------------------------------------------------------
// Kernel 2b: merge split-K partials -> y[b][n][o] (normalized fp16).
// ---------------------------------------------------------------------------
__global__ __launch_bounds__(256) void merge_kernel(
    const unsigned short* __restrict__ partO,
    const float* __restrict__ pm, const float* __restrict__ pl,
    unsigned short* __restrict__ y,
    int S)
{
    int idx = blockIdx.x * 256 + threadIdx.x;
    int bn  = idx >> 5;
    int og  = idx & 31;
    const int BN = B_ * N_;

    float M = -INFINITY;
    for (int s = 0; s < S; s++) M = fmaxf(M, pm[(size_t)s * BN + bn]);
    float w[4];
    float L = 0.f;
    for (int s = 0; s < S; s++) {
        w[s] = __expf(pm[(size_t)s * BN + bn] - M);
        L += w[s] * pl[(size_t)s * BN + bn];
    }
    float inv = 1.0f / L;

    float a0 = 0.f, a1 = 0.f, a2 = 0.f, a3 = 0.f;
    for (int s = 0; s < S; s++) {
        us4 v = *(const us4*)(partO + ((size_t)s * BN + bn) * O_ + og * 4);
        a0 += h2f(v.x) * w[s];
        a1 += h2f(v.y) * w[s];
        a2 += h2f(v.z) * w[s];
        a3 += h2f(v.w) * w[s];
    }
    us4 r;
    r.x = f2h(a0 * inv); r.y = f2h(a1 * inv);
    r.z = f2h(a2 * inv); r.w = f2h(a3 * inv);
    *(us4*)(y + (size_t)bn * O_ + og * 4) = r;
}

// ---------------------------------------------------------------------------
// Kernel 3: z[b][c][n] = sum_o wW[c][o] y[b][n][o] + bW[c] + x[b][c][n]
// ---------------------------------------------------------------------------
__global__ __launch_bounds__(256) void out_kernel(
    const unsigned short* __restrict__ y,
    const void* __restrict__ wW,
    const void* __restrict__ bW,
    const void* __restrict__ x,
    const int*  __restrict__ flag,
    void* __restrict__ z)
{
    const int isf32 = *flag;
    const int b  = blockIdx.z;
    const int c0 = blockIdx.y * 64;
    const int n0 = blockIdx.x * 128;
    const int tid  = threadIdx.x;
    const int wv   = tid >> 6, lane = tid & 63;
    const int quad = lane >> 4, l16 = lane & 15;

    __shared__ alignas(16) unsigned short Ys[128][136];
    __shared__ alignas(16) unsigned short Ws[64][136];

    for (int it = 0; it < 16; it++) {
        int l = it * 256 + tid;
        int nn = l >> 5;
        int og = l & 31;
        us4 v = *(const us4*)(y + (size_t)(b * N_ + n0 + nn) * O_ + og * 4);
        *(us4*)&Ys[nn][og * 4] = v;
    }
    for (int it = 0; it < 8; it++) {
        int l = it * 256 + tid;
        int cc = l >> 5;
        int og = l & 31;
        float v[4];
        load4f(wW, (size_t)(c0 + cc) * O_ + og * 4, isf32, v);
        Ws[cc][og * 4 + 0] = f2h(v[0]);
        Ws[cc][og * 4 + 1] = f2h(v[1]);
        Ws[cc][og * 4 + 2] = f2h(v[2]);
        Ws[cc][og * 4 + 3] = f2h(v[3]);
    }
    __syncthreads();

    f32x4 acc[8];
    for (int i = 0; i < 8; i++) acc[i] = (f32x4)0.f;
    for (int s = 0; s < 4; s++) {
        f16x8 a = *(const f16x8*)&Ws[wv * 16 + l16][s * 32 + quad * 8];
        for (int nt = 0; nt < 8; nt++) {
            f16x8 bb = *(const f16x8*)&Ys[nt * 16 + l16][s * 32 + quad * 8];
            acc[nt] = __builtin_amdgcn_mfma_f32_16x16x32_f16(a, bb, acc[nt], 0, 0, 0);
        }
    }
    for (int r = 0; r < 4; r++) {
        int c = c0 + wv * 16 + quad * 4 + r;
        float bias = load1f(bW, c, isf32);
        for (int nt = 0; nt < 8; nt++) {
            int n = n0 + nt * 16 + l16;
            size_t idx = (size_t)(b * C_ + c) * N_ + n;
            float zv = acc[nt][r] + bias + load1f(x, idx, isf32);
            if (isf32) ((float*)z)[idx] = zv;
            else       ((unsigned short*)z)[idx] = f2bf(zv);
        }
    }
}

// ---------------------------------------------------------------------------
extern "C" void kernel_launch(void* const* d_in, const int* in_sizes, int n_in,
                              void* d_out, int out_size, void* d_ws, size_t ws_size,
                              hipStream_t stream) {
    const void* x  = d_in[0];
    const void* wt = d_in[1];
    const void* bt = d_in[2];
    const void* wp = d_in[3];
    const void* bp = d_in[4];
    const void* wg = d_in[5];
    const void* bg = d_in[6];
    const void* wW = d_in[7];
    const void* bW = d_in[8];

    // split factor from ws_size (constant across calls -> graph-safe)
    const size_t base = 64 + 8388608 /*thph*/ + 4194304 /*gT*/;
    const size_t per_split = 4194304 /*partO*/ + 131072 /*pm+pl*/;
    int S = 4;   // 512 blocks -> 2 blocks/CU
    while (S > 1 && base + (size_t)S * per_split > ws_size) S--;

    char* p = (char*)d_ws;
    int* flag = (int*)p;                    p += 64;
    unsigned short* thph = (unsigned short*)p;  p += 8388608;
    unsigned short* gT   = (unsigned short*)p;  p += 4194304;
    unsigned short* partO = (unsigned short*)p; p += (size_t)S * 4194304;
    float* pm = (float*)p;                  p += (size_t)S * 65536;
    float* pl = (float*)p;
    unsigned short* y = gT;   // gT dead after attn_partial; reuse for y

    detect_kernel<<<1, 256, 0, stream>>>((const unsigned short*)x, flag);

    dim3 g1(N_ / 64, 3, B_);
    qkv_kernel<<<g1, 256, 0, stream>>>(x, wt, wp, wg, bt, bp, bg, flag, thph, gT);

    dim3 g2(N_ / 128, S, B_);
    attn_partial<<<g2, 512, 0, stream>>>(thph, gT, partO, pm, pl, S);

    merge_kernel<<<(B_ * N_ * 32) / 256, 256, 0, stream>>>(partO, pm, pl, y, S);

    dim3 g3(N_ / 128, C_ / 64, B_);
    out_kernel<<<g3, 256, 0, stream>>>(y, wW, bW, x, flag, d_out);
}